// Round 5
// baseline (707.557 us; speedup 1.0000x reference)
//
#include <hip/hip_runtime.h>
#include <cstdint>
#include <cstddef>

#define NCENT   100000
#define DIM     128
#define BATCH   1024
#define NCLASS  100
#define KNEIGH  200
#define GC      0.005f          // 1/(2*sigma^2), sigma=10
#define HIST_MAX 160            // only histogram bins < 160 (s < 96); cut ~ bin 113
#define MARGIN   8              // candidate window: bin <= cutbin + 8 (covers 2*eps+1)
#define CAND_CAP 2048
#define QSPLIT   8              // row-chunks for hist/gather kernels

typedef __attribute__((ext_vector_type(8))) short s8v;   // 8 bf16
typedef __attribute__((ext_vector_type(4))) float f4v;   // 4 f32 acc

static __device__ __forceinline__ unsigned short f2bf(float x) {
    uint32_t b = __float_as_uint(x);
    uint32_t r = (b + 0x7fffu + ((b >> 16) & 1u)) >> 16;   // RNE
    return (unsigned short)r;
}

// ---- replicate numpy AVX512 pairwise sum of x[k]^2, k=0..127 (round-3 verified) ----
__device__ __forceinline__ float np_sum128_sq(const float* __restrict__ x) {
#pragma clang fp contract(off)
    float v[16];
#pragma unroll
    for (int l = 0; l < 16; ++l) {
        float q0 = x[l]       * x[l];
        float q1 = x[16 + l]  * x[16 + l];
        float q2 = x[32 + l]  * x[32 + l];
        float q3 = x[48 + l]  * x[48 + l];
        float q4 = x[64 + l]  * x[64 + l];
        float q5 = x[80 + l]  * x[80 + l];
        float q6 = x[96 + l]  * x[96 + l];
        float q7 = x[112 + l] * x[112 + l];
        v[l] = ((q0 + q1) + (q2 + q3)) + ((q4 + q5) + (q6 + q7));
    }
    float t0 = v[0] + v[8],  t1 = v[1] + v[9],  t2 = v[2] + v[10], t3 = v[3] + v[11];
    float t4 = v[4] + v[12], t5 = v[5] + v[13], t6 = v[6] + v[14], t7 = v[7] + v[15];
    float u0 = t0 + t4, u1 = t1 + t5, u2 = t2 + t6, u3 = t3 + t7;
    float p0 = u0 + u2, p1 = u1 + u3;
    return p0 + p1;
}

// ---- prep: centres f32 -> bf16 + fp32 norms. 8 threads/centre, 32 centres/block ----
__global__ __launch_bounds__(256) void prep_cent_kernel(
    const float* __restrict__ cent, unsigned short* __restrict__ centb,
    float* __restrict__ cnorm) {
    const int t = threadIdx.x;
    const int c = blockIdx.x * 32 + (t >> 3);   // grid 3125 * 32 = 100000 exact
    const int p = t & 7;
    const float4* src = (const float4*)(cent + (size_t)c * DIM + p * 16);
    float s = 0.f;
    unsigned short tmp[16];
#pragma unroll
    for (int j = 0; j < 4; ++j) {
        float4 v = src[j];
        s += v.x * v.x + v.y * v.y + v.z * v.z + v.w * v.w;
        tmp[4 * j + 0] = f2bf(v.x); tmp[4 * j + 1] = f2bf(v.y);
        tmp[4 * j + 2] = f2bf(v.z); tmp[4 * j + 3] = f2bf(v.w);
    }
    s += __shfl_xor(s, 1); s += __shfl_xor(s, 2); s += __shfl_xor(s, 4);
    if (p == 0) cnorm[c] = s;
    uint4 o0, o1;
    o0.x = (uint32_t)tmp[0]  | ((uint32_t)tmp[1]  << 16);
    o0.y = (uint32_t)tmp[2]  | ((uint32_t)tmp[3]  << 16);
    o0.z = (uint32_t)tmp[4]  | ((uint32_t)tmp[5]  << 16);
    o0.w = (uint32_t)tmp[6]  | ((uint32_t)tmp[7]  << 16);
    o1.x = (uint32_t)tmp[8]  | ((uint32_t)tmp[9]  << 16);
    o1.y = (uint32_t)tmp[10] | ((uint32_t)tmp[11] << 16);
    o1.z = (uint32_t)tmp[12] | ((uint32_t)tmp[13] << 16);
    o1.w = (uint32_t)tmp[14] | ((uint32_t)tmp[15] << 16);
    uint4* dst = (uint4*)(centb + (size_t)c * DIM + p * 16);
    dst[0] = o0; dst[1] = o1;
}

// ---- prep: feat f32 -> bf16 + np-replicated |f|^2 per row ----
__global__ __launch_bounds__(256) void prep_feat_kernel(
    const float* __restrict__ feat, unsigned short* __restrict__ featb,
    float* __restrict__ fnrep) {
    const int r = blockIdx.x * 256 + threadIdx.x;
    if (r >= BATCH) return;
    const float* fp = feat + (size_t)r * DIM;
    fnrep[r] = np_sum128_sq(fp);
    unsigned short* dst = featb + (size_t)r * DIM;
    for (int k = 0; k < DIM; ++k) dst[k] = f2bf(fp[k]);
}

// ---- coarse distance via bf16 MFMA: qmat[row][col] = clamp(floor(cn - 2*dot) + 64) ----
__global__ __launch_bounds__(256, 2) void mfma_coarse_kernel(
    const unsigned short* __restrict__ featb, const unsigned short* __restrict__ centb,
    const float* __restrict__ cnorm, unsigned char* __restrict__ qmat) {
    const int w = threadIdx.x >> 6;
    const int lane = threadIdx.x & 63;
    const int lrow = lane & 15;
    const int lk = (lane >> 4) * 8;
    const int row0 = blockIdx.y * 128;
    const int colbase = blockIdx.x * 512;

    s8v a[8][4];
#pragma unroll
    for (int rs = 0; rs < 8; ++rs)
#pragma unroll
        for (int ks = 0; ks < 4; ++ks)
            a[rs][ks] = *(const s8v*)(featb + (size_t)(row0 + rs * 16 + lrow) * DIM + ks * 32 + lk);

    for (int it = 0; it < 8; ++it) {
        const int c0 = colbase + it * 64 + w * 16;
        const int ccol = c0 + lrow;
        const int cc = ccol < NCENT ? ccol : NCENT - 1;
        const bool valid = (ccol < NCENT);

        f4v acc[8];
#pragma unroll
        for (int rs = 0; rs < 8; ++rs) acc[rs] = (f4v){0.f, 0.f, 0.f, 0.f};

#pragma unroll
        for (int ks = 0; ks < 4; ++ks) {
            s8v b = *(const s8v*)(centb + (size_t)cc * DIM + ks * 32 + lk);
#pragma unroll
            for (int rs = 0; rs < 8; ++rs)
                acc[rs] = __builtin_amdgcn_mfma_f32_16x16x32_bf16(a[rs][ks], b, acc[rs], 0, 0, 0);
        }

        const float cn = cnorm[cc];
        if (valid) {
#pragma unroll
            for (int rs = 0; rs < 8; ++rs) {
#pragma unroll
                for (int j = 0; j < 4; ++j) {
                    float s = cn - 2.0f * acc[rs][j];
                    int bin = (int)floorf(s) + 64;
                    bin = bin < 0 ? 0 : (bin > 255 ? 255 : bin);
                    int row = row0 + rs * 16 + (lane >> 4) * 4 + j;
                    qmat[(size_t)row * NCENT + ccol] = (unsigned char)bin;
                }
            }
        }
    }
}

// ---- hist160: per-row 160-bin histogram, QSPLIT blocks per row ----
__global__ __launch_bounds__(256) void hist160_kernel(
    const unsigned char* __restrict__ qmat, unsigned int* __restrict__ rowhist) {
    __shared__ unsigned int h[HIST_MAX];
    const int t = threadIdx.x;
    for (int i = t; i < HIST_MAX; i += 256) h[i] = 0;
    __syncthreads();

    const int row = blockIdx.x;
    const int part = blockIdx.y;
    const int chunk = NCENT / QSPLIT;            // 12500 bytes, %4 == 0
    const uint32_t* p = (const uint32_t*)(qmat + (size_t)row * NCENT + (size_t)part * chunk);
    const int n32 = chunk / 4;                   // 3125
    for (int i = t; i < n32; i += 256) {
        uint32_t v = p[i];
        unsigned b0 = v & 255u, b1 = (v >> 8) & 255u, b2 = (v >> 16) & 255u, b3 = v >> 24;
        if (b0 < HIST_MAX) atomicAdd(&h[b0], 1u);
        if (b1 < HIST_MAX) atomicAdd(&h[b1], 1u);
        if (b2 < HIST_MAX) atomicAdd(&h[b2], 1u);
        if (b3 < HIST_MAX) atomicAdd(&h[b3], 1u);
    }
    __syncthreads();
    unsigned int* gh = rowhist + (size_t)row * HIST_MAX;
    for (int i = t; i < HIST_MAX; i += 256)
        if (h[i]) atomicAdd(&gh[i], h[i]);
}

// ---- cut: per-row candidate threshold = cutbin + MARGIN ----
__global__ __launch_bounds__(256) void cut_kernel(
    const unsigned int* __restrict__ rowhist, unsigned int* __restrict__ thr) {
    const int row = blockIdx.x * 256 + threadIdx.x;
    if (row >= BATCH) return;
    const unsigned int* h = rowhist + (size_t)row * HIST_MAX;
    unsigned int cum = 0; int cutbin = HIST_MAX - 1;
    for (int b = 0; b < HIST_MAX; ++b) {
        cum += h[b];
        if (cum >= KNEIGH) { cutbin = b; break; }
    }
    int tv = cutbin + MARGIN;
    thr[row] = (unsigned int)(tv > 255 ? 255 : tv);
}

// ---- gather: append candidate indices (bin <= thr[row]) to per-row lists ----
__global__ __launch_bounds__(256) void gather_kernel(
    const unsigned char* __restrict__ qmat, const unsigned int* __restrict__ thr,
    unsigned int* __restrict__ candList, unsigned int* __restrict__ candCnt) {
    const int row = blockIdx.x;
    const int part = blockIdx.y;
    const unsigned int tv = thr[row];
    const int chunk = NCENT / QSPLIT;
    const int base = part * chunk;
    const uint32_t* p = (const uint32_t*)(qmat + (size_t)row * NCENT + (size_t)base);
    const int n32 = chunk / 4;
    unsigned int* list = candList + (size_t)row * CAND_CAP;
    for (int i = threadIdx.x; i < n32; i += 256) {
        uint32_t v = p[i];
#pragma unroll
        for (int sub = 0; sub < 4; ++sub) {
            unsigned b = (v >> (8 * sub)) & 255u;
            if (b <= tv) {
                unsigned int pos = atomicAdd(&candCnt[row], 1u);
                if (pos < CAND_CAP) list[pos] = (unsigned int)(base + 4 * i + sub);
            }
        }
    }
}

// ---- refine: exact np-fp32 keys, top-200 by (key, idx), weights, normalize ----
__global__ __launch_bounds__(256) void refine_kernel(
    const unsigned int* __restrict__ candList, const unsigned int* __restrict__ candCnt,
    const float* __restrict__ feat, const float* __restrict__ cent,
    const float* __restrict__ fnrep,
    const float* __restrict__ kw, const int* __restrict__ labels,
    float* __restrict__ out) {

    __shared__ float fsh[DIM];
    __shared__ int   candI[CAND_CAP];
    __shared__ float candKey[CAND_CAP];
    __shared__ float p[NCLASS];
    __shared__ float ssum;

    const int t = threadIdx.x;
    const int row = blockIdx.x;
    const unsigned int ncu = candCnt[row];
    const int nc = (int)(ncu < CAND_CAP ? ncu : CAND_CAP);

    for (int i = t; i < DIM; i += 256) fsh[i] = feat[(size_t)row * DIM + i];
    for (int i = t; i < NCLASS; i += 256) p[i] = 0.f;
    const unsigned int* list = candList + (size_t)row * CAND_CAP;
    for (int i = t; i < nc; i += 256) candI[i] = (int)list[i];
    __syncthreads();

    const float fnr = fnrep[row];

    // np-fp32 replicated keys
    for (int ci = t; ci < nc; ci += 256) {
        const int idx = candI[ci];
        const float* cp = cent + (size_t)idx * DIM;
        float acc = 0.f;
#pragma unroll
        for (int k = 0; k < DIM; ++k) acc = fmaf(2.0f * fsh[k], cp[k], acc);
        float cnrep = np_sum128_sq(cp);
        {
#pragma clang fp contract(off)
            candKey[ci] = (fnr - acc) + cnrep;
        }
    }
    __syncthreads();

    // exact top-200 by (key, idx); fp64 distance + weight only for selected
    for (int ci = t; ci < nc; ci += 256) {
        const float ki = candKey[ci];
        const int ii = candI[ci];
        int rank = 0;
        for (int j = 0; j < nc; ++j) {
            if (j == ci) continue;
            float kj = candKey[j];
            if (kj < ki || (kj == ki && candI[j] < ii)) rank++;
        }
        if (rank < KNEIGH) {
            const float* cp = cent + (size_t)ii * DIM;
            double dd = 0.0;
            for (int k = 0; k < DIM; ++k) {
                double d1 = (double)fsh[k] - (double)cp[k];
                dd += d1 * d1;
            }
            float wv = expf(kw[ii] - (float)dd * GC);
            atomicAdd(&p[labels[ii]], wv);
        }
    }
    __syncthreads();

    if (t == 0) {
        float s = 0.f;
        for (int c = 0; c < NCLASS; ++c) {
            float v = p[c];
            v = (v == 0.f) ? 1e-10f : v;
            p[c] = v;
            s += v;
        }
        ssum = s;
    }
    __syncthreads();
    for (int c = t; c < NCLASS; c += 256)
        out[(size_t)row * NCLASS + c] = logf(p[c] / ssum);
}

static inline size_t align256(size_t x) { return (x + 255) & ~(size_t)255; }

extern "C" void kernel_launch(void* const* d_in, const int* in_sizes, int n_in,
                              void* d_out, int out_size, void* d_ws, size_t ws_size,
                              hipStream_t stream) {
    const float* feat   = (const float*)d_in[0];  // [1024,128]
    const float* cent   = (const float*)d_in[1];  // [100000,128]
    const float* kw     = (const float*)d_in[2];  // [100000]
    const int*   labels = (const int*)d_in[3];    // [100000]
    float* out = (float*)d_out;                   // [1024,100]

    char* base = (char*)d_ws;
    size_t o = 0;
    unsigned short* centb  = (unsigned short*)(base + o); o += align256((size_t)NCENT * DIM * 2);
    unsigned short* featb  = (unsigned short*)(base + o); o += align256((size_t)BATCH * DIM * 2);
    float* cnorm           = (float*)(base + o);          o += align256((size_t)NCENT * 4);
    float* fnrep           = (float*)(base + o);          o += align256((size_t)BATCH * 4);
    unsigned char* qmat    = (unsigned char*)(base + o);  o += align256((size_t)BATCH * NCENT);
    unsigned int* rowhist  = (unsigned int*)(base + o);   o += align256((size_t)BATCH * HIST_MAX * 4);
    unsigned int* thr      = (unsigned int*)(base + o);   o += align256((size_t)BATCH * 4);
    unsigned int* candCnt  = (unsigned int*)(base + o);   o += align256((size_t)BATCH * 4);
    unsigned int* candList = (unsigned int*)(base + o);   o += align256((size_t)BATCH * CAND_CAP * 4);
    (void)ws_size; (void)in_sizes; (void)n_in; (void)out_size;

    prep_cent_kernel<<<NCENT / 32, 256, 0, stream>>>(cent, centb, cnorm);
    prep_feat_kernel<<<(BATCH + 255) / 256, 256, 0, stream>>>(feat, featb, fnrep);

    dim3 gg((NCENT + 511) / 512, BATCH / 128);   // 196 x 8
    mfma_coarse_kernel<<<gg, 256, 0, stream>>>(featb, centb, cnorm, qmat);

    hipMemsetAsync(rowhist, 0, (size_t)BATCH * HIST_MAX * 4, stream);
    hipMemsetAsync(candCnt, 0, (size_t)BATCH * 4, stream);

    dim3 gh(BATCH, QSPLIT);
    hist160_kernel<<<gh, 256, 0, stream>>>(qmat, rowhist);
    cut_kernel<<<BATCH / 256, 256, 0, stream>>>(rowhist, thr);
    gather_kernel<<<gh, 256, 0, stream>>>(qmat, thr, candList, candCnt);
    refine_kernel<<<BATCH, 256, 0, stream>>>(candList, candCnt, feat, cent, fnrep,
                                             kw, labels, out);
}

// Round 6
// 347.329 us; speedup vs baseline: 2.0371x; 2.0371x over previous
//
#include <hip/hip_runtime.h>
#include <cstdint>
#include <cstddef>

#define NCENT   100000
#define DIM     128
#define BATCH   1024
#define NCLASS  100
#define KNEIGH  200
#define GC      0.005f          // 1/(2*sigma^2), sigma=10
#define HIST_MAX 160            // histogram bins < 160; cut ~ bin 113
#define MARGIN   8              // candidate window: bin <= cutbin + 8 (covers bf16 eps)
#define CAND_CAP 2048
#define BAND_CAP 128
#define BAND_M   0.015f         // np-vs-fp64 ambiguity margin (bound ~1e-3, 15x slack)

typedef __attribute__((ext_vector_type(8))) short s8v;   // 8 bf16
typedef __attribute__((ext_vector_type(4))) float f4v;   // 4 f32 acc

static __device__ __forceinline__ unsigned short f2bf(float x) {
    uint32_t b = __float_as_uint(x);
    uint32_t r = (b + 0x7fffu + ((b >> 16) & 1u)) >> 16;   // RNE
    return (unsigned short)r;
}

// ---- replicate numpy AVX512 pairwise sum of x[k]^2, k=0..127 (round-3 verified) ----
__device__ __forceinline__ float np_sum128_sq(const float* __restrict__ x) {
#pragma clang fp contract(off)
    float v[16];
#pragma unroll
    for (int l = 0; l < 16; ++l) {
        float q0 = x[l]       * x[l];
        float q1 = x[16 + l]  * x[16 + l];
        float q2 = x[32 + l]  * x[32 + l];
        float q3 = x[48 + l]  * x[48 + l];
        float q4 = x[64 + l]  * x[64 + l];
        float q5 = x[80 + l]  * x[80 + l];
        float q6 = x[96 + l]  * x[96 + l];
        float q7 = x[112 + l] * x[112 + l];
        v[l] = ((q0 + q1) + (q2 + q3)) + ((q4 + q5) + (q6 + q7));
    }
    float t0 = v[0] + v[8],  t1 = v[1] + v[9],  t2 = v[2] + v[10], t3 = v[3] + v[11];
    float t4 = v[4] + v[12], t5 = v[5] + v[13], t6 = v[6] + v[14], t7 = v[7] + v[15];
    float u0 = t0 + t4, u1 = t1 + t5, u2 = t2 + t6, u3 = t3 + t7;
    float p0 = u0 + u2, p1 = u1 + u3;
    return p0 + p1;
}

// ---- prep: centres f32 -> bf16 + fp32 norms ----
__global__ __launch_bounds__(256) void prep_cent_kernel(
    const float* __restrict__ cent, unsigned short* __restrict__ centb,
    float* __restrict__ cnorm) {
    const int t = threadIdx.x;
    const int c = blockIdx.x * 32 + (t >> 3);
    const int p = t & 7;
    const float4* src = (const float4*)(cent + (size_t)c * DIM + p * 16);
    float s = 0.f;
    unsigned short tmp[16];
#pragma unroll
    for (int j = 0; j < 4; ++j) {
        float4 v = src[j];
        s += v.x * v.x + v.y * v.y + v.z * v.z + v.w * v.w;
        tmp[4 * j + 0] = f2bf(v.x); tmp[4 * j + 1] = f2bf(v.y);
        tmp[4 * j + 2] = f2bf(v.z); tmp[4 * j + 3] = f2bf(v.w);
    }
    s += __shfl_xor(s, 1); s += __shfl_xor(s, 2); s += __shfl_xor(s, 4);
    if (p == 0) cnorm[c] = s;
    uint4 o0, o1;
    o0.x = (uint32_t)tmp[0]  | ((uint32_t)tmp[1]  << 16);
    o0.y = (uint32_t)tmp[2]  | ((uint32_t)tmp[3]  << 16);
    o0.z = (uint32_t)tmp[4]  | ((uint32_t)tmp[5]  << 16);
    o0.w = (uint32_t)tmp[6]  | ((uint32_t)tmp[7]  << 16);
    o1.x = (uint32_t)tmp[8]  | ((uint32_t)tmp[9]  << 16);
    o1.y = (uint32_t)tmp[10] | ((uint32_t)tmp[11] << 16);
    o1.z = (uint32_t)tmp[12] | ((uint32_t)tmp[13] << 16);
    o1.w = (uint32_t)tmp[14] | ((uint32_t)tmp[15] << 16);
    uint4* dst = (uint4*)(centb + (size_t)c * DIM + p * 16);
    dst[0] = o0; dst[1] = o1;
}

// ---- prep: feat f32 -> bf16 + np-replicated |f|^2 per row ----
__global__ __launch_bounds__(256) void prep_feat_kernel(
    const float* __restrict__ feat, unsigned short* __restrict__ featb,
    float* __restrict__ fnrep) {
    const int r = blockIdx.x * 256 + threadIdx.x;
    if (r >= BATCH) return;
    const float* fp = feat + (size_t)r * DIM;
    fnrep[r] = np_sum128_sq(fp);
    unsigned short* dst = featb + (size_t)r * DIM;
    for (int k = 0; k < DIM; ++k) dst[k] = f2bf(fp[k]);
}

// ---- coarse distance via bf16 MFMA: qmat[row][col] = clamp(floor(cn - 2*dot) + 64) ----
__global__ __launch_bounds__(256, 2) void mfma_coarse_kernel(
    const unsigned short* __restrict__ featb, const unsigned short* __restrict__ centb,
    const float* __restrict__ cnorm, unsigned char* __restrict__ qmat) {
    const int w = threadIdx.x >> 6;
    const int lane = threadIdx.x & 63;
    const int lrow = lane & 15;
    const int lk = (lane >> 4) * 8;
    const int row0 = blockIdx.y * 128;
    const int colbase = blockIdx.x * 512;

    s8v a[8][4];
#pragma unroll
    for (int rs = 0; rs < 8; ++rs)
#pragma unroll
        for (int ks = 0; ks < 4; ++ks)
            a[rs][ks] = *(const s8v*)(featb + (size_t)(row0 + rs * 16 + lrow) * DIM + ks * 32 + lk);

    for (int it = 0; it < 8; ++it) {
        const int c0 = colbase + it * 64 + w * 16;
        const int ccol = c0 + lrow;
        const int cc = ccol < NCENT ? ccol : NCENT - 1;
        const bool valid = (ccol < NCENT);

        f4v acc[8];
#pragma unroll
        for (int rs = 0; rs < 8; ++rs) acc[rs] = (f4v){0.f, 0.f, 0.f, 0.f};

#pragma unroll
        for (int ks = 0; ks < 4; ++ks) {
            s8v b = *(const s8v*)(centb + (size_t)cc * DIM + ks * 32 + lk);
#pragma unroll
            for (int rs = 0; rs < 8; ++rs)
                acc[rs] = __builtin_amdgcn_mfma_f32_16x16x32_bf16(a[rs][ks], b, acc[rs], 0, 0, 0);
        }

        const float cn = cnorm[cc];
        if (valid) {
#pragma unroll
            for (int rs = 0; rs < 8; ++rs) {
#pragma unroll
                for (int j = 0; j < 4; ++j) {
                    float s = cn - 2.0f * acc[rs][j];
                    int bin = (int)floorf(s) + 64;
                    bin = bin < 0 ? 0 : (bin > 255 ? 255 : bin);
                    int row = row0 + rs * 16 + (lane >> 4) * 4 + j;
                    qmat[(size_t)row * NCENT + ccol] = (unsigned char)bin;
                }
            }
        }
    }
}

// ---- selectprep: per-row hist + cut + gather in ONE kernel (row is L2-hot on 2nd pass) ----
__global__ __launch_bounds__(256) void selectprep_kernel(
    const unsigned char* __restrict__ qmat,
    unsigned int* __restrict__ candList, unsigned int* __restrict__ candCnt) {
    __shared__ unsigned int h[HIST_MAX];
    __shared__ int thr_s;
    __shared__ int nc_s;

    const int t = threadIdx.x;
    const int row = blockIdx.x;
    const uint32_t* qp = (const uint32_t*)(qmat + (size_t)row * NCENT);
    const int n32 = NCENT / 4;   // 25000

    for (int i = t; i < HIST_MAX; i += 256) h[i] = 0;
    if (t == 0) nc_s = 0;
    __syncthreads();

    for (int i = t; i < n32; i += 256) {
        uint32_t v = qp[i];
        unsigned b0 = v & 255u, b1 = (v >> 8) & 255u, b2 = (v >> 16) & 255u, b3 = v >> 24;
        if (b0 < HIST_MAX) atomicAdd(&h[b0], 1u);
        if (b1 < HIST_MAX) atomicAdd(&h[b1], 1u);
        if (b2 < HIST_MAX) atomicAdd(&h[b2], 1u);
        if (b3 < HIST_MAX) atomicAdd(&h[b3], 1u);
    }
    __syncthreads();
    if (t == 0) {
        unsigned int cum = 0; int cutbin = HIST_MAX - 1;
        for (int b = 0; b < HIST_MAX; ++b) {
            cum += h[b];
            if (cum >= KNEIGH) { cutbin = b; break; }
        }
        int tv = cutbin + MARGIN;
        thr_s = tv > 255 ? 255 : tv;
    }
    __syncthreads();
    const unsigned tv = (unsigned)thr_s;
    unsigned int* list = candList + (size_t)row * CAND_CAP;

    for (int i = t; i < n32; i += 256) {
        uint32_t v = qp[i];
#pragma unroll
        for (int sub = 0; sub < 4; ++sub) {
            unsigned b = (v >> (8 * sub)) & 255u;
            if (b <= tv) {
                int pos = atomicAdd(&nc_s, 1);
                if (pos < CAND_CAP) list[pos] = (unsigned int)(4 * i + sub);
            }
        }
    }
    __syncthreads();
    if (t == 0) candCnt[row] = (unsigned int)(nc_s < CAND_CAP ? nc_s : CAND_CAP);
}

// ---- refine v2: coalesced fp64 distances, margin band -> np-exact only when needed ----
__global__ __launch_bounds__(256) void refine_kernel(
    const unsigned int* __restrict__ candList, const unsigned int* __restrict__ candCnt,
    const float* __restrict__ feat, const float* __restrict__ cent,
    const float* __restrict__ fnrep,
    const float* __restrict__ kw, const int* __restrict__ labels,
    float* __restrict__ out) {

    __shared__ float fsh[DIM];
    __shared__ int   candI[CAND_CAP];
    __shared__ float dist[CAND_CAP];
    __shared__ float p[NCLASS];
    __shared__ float cutVal_s;
    __shared__ int   nIn_s, nBand_s;
    __shared__ int   bandCi[BAND_CAP];
    __shared__ float bandKey[BAND_CAP];
    __shared__ float ssum;

    const int t = threadIdx.x;
    const int row = blockIdx.x;
    const unsigned int ncu = candCnt[row];
    const int nc = (int)(ncu < CAND_CAP ? ncu : CAND_CAP);

    for (int i = t; i < DIM; i += 256) fsh[i] = feat[(size_t)row * DIM + i];
    for (int i = t; i < NCLASS; i += 256) p[i] = 0.f;
    if (t == 0) { nIn_s = 0; nBand_s = 0; cutVal_s = 3.4e38f; }
    const unsigned int* list = candList + (size_t)row * CAND_CAP;
    for (int i = t; i < nc; i += 256) candI[i] = (int)list[i];
    __syncthreads();

    // Phase A: fp64 distance, 16 lanes per candidate, coalesced 512B row reads
    const int g = t >> 4;     // group 0..15
    const int gl = t & 15;    // lane within group
    double fr[8];
    {
        const float* fpl = fsh + gl * 8;
#pragma unroll
        for (int j = 0; j < 8; ++j) fr[j] = (double)fpl[j];
    }
    for (int ci = g; ci < nc; ci += 16) {
        const float* cp = cent + (size_t)candI[ci] * DIM + gl * 8;
        float4 c0 = ((const float4*)cp)[0];
        float4 c1 = ((const float4*)cp)[1];
        double d0 = fr[0] - (double)c0.x; double a = d0 * d0;
        double d1 = fr[1] - (double)c0.y; a = fma(d1, d1, a);
        double d2 = fr[2] - (double)c0.z; a = fma(d2, d2, a);
        double d3 = fr[3] - (double)c0.w; a = fma(d3, d3, a);
        double d4 = fr[4] - (double)c1.x; a = fma(d4, d4, a);
        double d5 = fr[5] - (double)c1.y; a = fma(d5, d5, a);
        double d6 = fr[6] - (double)c1.z; a = fma(d6, d6, a);
        double d7 = fr[7] - (double)c1.w; a = fma(d7, d7, a);
        a += __shfl_xor(a, 8, 16);
        a += __shfl_xor(a, 4, 16);
        a += __shfl_xor(a, 2, 16);
        a += __shfl_xor(a, 1, 16);
        if (gl == 0) dist[ci] = (float)a;
    }
    __syncthreads();

    // Phase B: provisional rank by (dist, idx); find 200th value
    for (int ci = t; ci < nc; ci += 256) {
        const float ki = dist[ci];
        const int ii = candI[ci];
        int rank = 0;
        for (int j = 0; j < nc; ++j) {
            float kj = dist[j];
            if (kj < ki || (kj == ki && candI[j] < ii)) rank++;
        }
        if (rank == KNEIGH - 1) cutVal_s = ki;
    }
    __syncthreads();
    const float cutVal = cutVal_s;   // +inf if nc <= K -> everything def-in

    // Phase C: classify def-in / band / def-out
    for (int ci = t; ci < nc; ci += 256) {
        const float d = dist[ci];
        if (d < cutVal - BAND_M) {
            atomicAdd(&nIn_s, 1);
            const int ii = candI[ci];
            float wv = expf(kw[ii] - d * GC);
            atomicAdd(&p[labels[ii]], wv);
        } else if (d <= cutVal + BAND_M) {
            int pos = atomicAdd(&nBand_s, 1);
            if (pos < BAND_CAP) bandCi[pos] = ci;
        }
    }
    __syncthreads();
    const int nIn = nIn_s;
    const int nBand = nBand_s < BAND_CAP ? nBand_s : BAND_CAP;
    const int needB = KNEIGH - nIn;
    const float fnr = fnrep[row];

    // Phase D: np-exact keys for band members only (rows are L2-hot from Phase A)
    for (int i = t; i < nBand; i += 256) {
        const int idx = candI[bandCi[i]];
        const float* cp = cent + (size_t)idx * DIM;
        float acc = 0.f;
#pragma unroll
        for (int k = 0; k < DIM; ++k) acc = fmaf(2.0f * fsh[k], cp[k], acc);
        float cn = np_sum128_sq(cp);
        {
#pragma clang fp contract(off)
            bandKey[i] = (fnr - acc) + cn;
        }
    }
    __syncthreads();

    // Phase E: take needB smallest (npKey, idx) from band
    for (int i = t; i < nBand; i += 256) {
        const float ki = bandKey[i];
        const int ii = candI[bandCi[i]];
        int rank = 0;
        for (int j = 0; j < nBand; ++j) {
            float kj = bandKey[j];
            if (kj < ki || (kj == ki && candI[bandCi[j]] < ii)) rank++;
        }
        if (rank < needB) {
            float wv = expf(kw[ii] - dist[bandCi[i]] * GC);
            atomicAdd(&p[labels[ii]], wv);
        }
    }
    __syncthreads();

    // Phase F: normalize + log
    if (t == 0) {
        float s = 0.f;
        for (int c = 0; c < NCLASS; ++c) {
            float v = p[c];
            v = (v == 0.f) ? 1e-10f : v;
            p[c] = v;
            s += v;
        }
        ssum = s;
    }
    __syncthreads();
    for (int c = t; c < NCLASS; c += 256)
        out[(size_t)row * NCLASS + c] = logf(p[c] / ssum);
}

static inline size_t align256(size_t x) { return (x + 255) & ~(size_t)255; }

extern "C" void kernel_launch(void* const* d_in, const int* in_sizes, int n_in,
                              void* d_out, int out_size, void* d_ws, size_t ws_size,
                              hipStream_t stream) {
    const float* feat   = (const float*)d_in[0];  // [1024,128]
    const float* cent   = (const float*)d_in[1];  // [100000,128]
    const float* kw     = (const float*)d_in[2];  // [100000]
    const int*   labels = (const int*)d_in[3];    // [100000]
    float* out = (float*)d_out;                   // [1024,100]

    char* base = (char*)d_ws;
    size_t o = 0;
    unsigned short* centb  = (unsigned short*)(base + o); o += align256((size_t)NCENT * DIM * 2);
    unsigned short* featb  = (unsigned short*)(base + o); o += align256((size_t)BATCH * DIM * 2);
    float* cnorm           = (float*)(base + o);          o += align256((size_t)NCENT * 4);
    float* fnrep           = (float*)(base + o);          o += align256((size_t)BATCH * 4);
    unsigned char* qmat    = (unsigned char*)(base + o);  o += align256((size_t)BATCH * NCENT);
    unsigned int* candCnt  = (unsigned int*)(base + o);   o += align256((size_t)BATCH * 4);
    unsigned int* candList = (unsigned int*)(base + o);   o += align256((size_t)BATCH * CAND_CAP * 4);
    (void)ws_size; (void)in_sizes; (void)n_in; (void)out_size;

    prep_cent_kernel<<<NCENT / 32, 256, 0, stream>>>(cent, centb, cnorm);
    prep_feat_kernel<<<(BATCH + 255) / 256, 256, 0, stream>>>(feat, featb, fnrep);

    dim3 gg((NCENT + 511) / 512, BATCH / 128);   // 196 x 8
    mfma_coarse_kernel<<<gg, 256, 0, stream>>>(featb, centb, cnorm, qmat);

    selectprep_kernel<<<BATCH, 256, 0, stream>>>(qmat, candList, candCnt);
    refine_kernel<<<BATCH, 256, 0, stream>>>(candList, candCnt, feat, cent, fnrep,
                                             kw, labels, out);
}

// Round 7
// 273.342 us; speedup vs baseline: 2.5885x; 1.2707x over previous
//
#include <hip/hip_runtime.h>
#include <cstdint>
#include <cstddef>

#define NCENT   100000
#define DIM     128
#define BATCH   1024
#define NCLASS  100
#define KNEIGH  200
#define GC      0.005f          // 1/(2*sigma^2), sigma=10
#define HIST_MAX 160            // histogram bins < 160; cut ~ bin 100-125
#define MARGIN   8              // candidate window: bin <= cutbin + 8 (covers bf16 eps)
#define CAND_CAP 2048
#define BAND_CAP 128
#define BAND_M   0.02f          // |npkey - dist32| bound ~1.3e-3, 15x slack

typedef __attribute__((ext_vector_type(8))) short s8v;   // 8 bf16
typedef __attribute__((ext_vector_type(4))) float f4v;   // 4 f32 acc

static __device__ __forceinline__ unsigned short f2bf(float x) {
    uint32_t b = __float_as_uint(x);
    uint32_t r = (b + 0x7fffu + ((b >> 16) & 1u)) >> 16;   // RNE
    return (unsigned short)r;
}

// ---- replicate numpy AVX512 pairwise sum of x[k]^2, k=0..127 (round-3 verified) ----
__device__ __forceinline__ float np_sum128_sq(const float* __restrict__ x) {
#pragma clang fp contract(off)
    float v[16];
#pragma unroll
    for (int l = 0; l < 16; ++l) {
        float q0 = x[l]       * x[l];
        float q1 = x[16 + l]  * x[16 + l];
        float q2 = x[32 + l]  * x[32 + l];
        float q3 = x[48 + l]  * x[48 + l];
        float q4 = x[64 + l]  * x[64 + l];
        float q5 = x[80 + l]  * x[80 + l];
        float q6 = x[96 + l]  * x[96 + l];
        float q7 = x[112 + l] * x[112 + l];
        v[l] = ((q0 + q1) + (q2 + q3)) + ((q4 + q5) + (q6 + q7));
    }
    float t0 = v[0] + v[8],  t1 = v[1] + v[9],  t2 = v[2] + v[10], t3 = v[3] + v[11];
    float t4 = v[4] + v[12], t5 = v[5] + v[13], t6 = v[6] + v[14], t7 = v[7] + v[15];
    float u0 = t0 + t4, u1 = t1 + t5, u2 = t2 + t6, u3 = t3 + t7;
    float p0 = u0 + u2, p1 = u1 + u3;
    return p0 + p1;
}

// ---- prep: centres f32 -> bf16 + fp32 norms ----
__global__ __launch_bounds__(256) void prep_cent_kernel(
    const float* __restrict__ cent, unsigned short* __restrict__ centb,
    float* __restrict__ cnorm) {
    const int t = threadIdx.x;
    const int c = blockIdx.x * 32 + (t >> 3);
    const int p = t & 7;
    const float4* src = (const float4*)(cent + (size_t)c * DIM + p * 16);
    float s = 0.f;
    unsigned short tmp[16];
#pragma unroll
    for (int j = 0; j < 4; ++j) {
        float4 v = src[j];
        s += v.x * v.x + v.y * v.y + v.z * v.z + v.w * v.w;
        tmp[4 * j + 0] = f2bf(v.x); tmp[4 * j + 1] = f2bf(v.y);
        tmp[4 * j + 2] = f2bf(v.z); tmp[4 * j + 3] = f2bf(v.w);
    }
    s += __shfl_xor(s, 1); s += __shfl_xor(s, 2); s += __shfl_xor(s, 4);
    if (p == 0) cnorm[c] = s;
    uint4 o0, o1;
    o0.x = (uint32_t)tmp[0]  | ((uint32_t)tmp[1]  << 16);
    o0.y = (uint32_t)tmp[2]  | ((uint32_t)tmp[3]  << 16);
    o0.z = (uint32_t)tmp[4]  | ((uint32_t)tmp[5]  << 16);
    o0.w = (uint32_t)tmp[6]  | ((uint32_t)tmp[7]  << 16);
    o1.x = (uint32_t)tmp[8]  | ((uint32_t)tmp[9]  << 16);
    o1.y = (uint32_t)tmp[10] | ((uint32_t)tmp[11] << 16);
    o1.z = (uint32_t)tmp[12] | ((uint32_t)tmp[13] << 16);
    o1.w = (uint32_t)tmp[14] | ((uint32_t)tmp[15] << 16);
    uint4* dst = (uint4*)(centb + (size_t)c * DIM + p * 16);
    dst[0] = o0; dst[1] = o1;
}

// ---- prep: feat f32 -> bf16 + np-replicated |f|^2 per row ----
__global__ __launch_bounds__(256) void prep_feat_kernel(
    const float* __restrict__ feat, unsigned short* __restrict__ featb,
    float* __restrict__ fnrep) {
    const int r = blockIdx.x * 256 + threadIdx.x;
    if (r >= BATCH) return;
    const float* fp = feat + (size_t)r * DIM;
    fnrep[r] = np_sum128_sq(fp);
    unsigned short* dst = featb + (size_t)r * DIM;
    for (int k = 0; k < DIM; ++k) dst[k] = f2bf(fp[k]);
}

// ---- coarse distance via bf16 MFMA: qmat[row][col] = clamp(floor(cn - 2*dot) + 64) ----
__global__ __launch_bounds__(256, 2) void mfma_coarse_kernel(
    const unsigned short* __restrict__ featb, const unsigned short* __restrict__ centb,
    const float* __restrict__ cnorm, unsigned char* __restrict__ qmat) {
    const int w = threadIdx.x >> 6;
    const int lane = threadIdx.x & 63;
    const int lrow = lane & 15;
    const int lk = (lane >> 4) * 8;
    const int row0 = blockIdx.y * 128;
    const int colbase = blockIdx.x * 512;

    s8v a[8][4];
#pragma unroll
    for (int rs = 0; rs < 8; ++rs)
#pragma unroll
        for (int ks = 0; ks < 4; ++ks)
            a[rs][ks] = *(const s8v*)(featb + (size_t)(row0 + rs * 16 + lrow) * DIM + ks * 32 + lk);

    for (int it = 0; it < 8; ++it) {
        const int c0 = colbase + it * 64 + w * 16;
        const int ccol = c0 + lrow;
        const int cc = ccol < NCENT ? ccol : NCENT - 1;
        const bool valid = (ccol < NCENT);

        f4v acc[8];
#pragma unroll
        for (int rs = 0; rs < 8; ++rs) acc[rs] = (f4v){0.f, 0.f, 0.f, 0.f};

#pragma unroll
        for (int ks = 0; ks < 4; ++ks) {
            s8v b = *(const s8v*)(centb + (size_t)cc * DIM + ks * 32 + lk);
#pragma unroll
            for (int rs = 0; rs < 8; ++rs)
                acc[rs] = __builtin_amdgcn_mfma_f32_16x16x32_bf16(a[rs][ks], b, acc[rs], 0, 0, 0);
        }

        const float cn = cnorm[cc];
        if (valid) {
#pragma unroll
            for (int rs = 0; rs < 8; ++rs) {
#pragma unroll
                for (int j = 0; j < 4; ++j) {
                    float s = cn - 2.0f * acc[rs][j];
                    int bin = (int)floorf(s) + 64;
                    bin = bin < 0 ? 0 : (bin > 255 ? 255 : bin);
                    int row = row0 + rs * 16 + (lane >> 4) * 4 + j;
                    qmat[(size_t)row * NCENT + ccol] = (unsigned char)bin;
                }
            }
        }
    }
}

// ---- fused select+refine: hist -> cut -> gather -> fp32 dist -> band -> np-exact -> out ----
__global__ __launch_bounds__(512, 8) void select_refine_kernel(
    const unsigned char* __restrict__ qmat,
    const float* __restrict__ feat, const float* __restrict__ cent,
    const float* __restrict__ fnrep,
    const float* __restrict__ kw, const int* __restrict__ labels,
    float* __restrict__ out) {

    __shared__ unsigned int h[HIST_MAX];
    __shared__ float fsh[DIM];
    __shared__ int   candI[CAND_CAP];
    __shared__ float dist[CAND_CAP];
    __shared__ float p[NCLASS];
    __shared__ int   thr_s, nc_s;
    __shared__ float cutVal_s;
    __shared__ int   nIn_s, nBand_s;
    __shared__ int   bandCi[BAND_CAP];
    __shared__ float bandKey[BAND_CAP];
    __shared__ float ssum;

    const int t = threadIdx.x;
    const int row = blockIdx.x;
    const uint4* qp = (const uint4*)(qmat + (size_t)row * NCENT);   // 100000 % 16 == 0
    const int n16 = NCENT / 16;                                     // 6250

    for (int i = t; i < HIST_MAX; i += 512) h[i] = 0;
    for (int i = t; i < DIM; i += 512) fsh[i] = feat[(size_t)row * DIM + i];
    for (int i = t; i < NCLASS; i += 512) p[i] = 0.f;
    if (t == 0) { nc_s = 0; nIn_s = 0; nBand_s = 0; cutVal_s = 3.4e38f; }
    __syncthreads();

    // pass 1: histogram of the low tail
    for (int i = t; i < n16; i += 512) {
        uint4 v4 = qp[i];
#pragma unroll
        for (int dw = 0; dw < 4; ++dw) {
            uint32_t v = (&v4.x)[dw];
            unsigned b0 = v & 255u, b1 = (v >> 8) & 255u, b2 = (v >> 16) & 255u, b3 = v >> 24;
            if (b0 < HIST_MAX) atomicAdd(&h[b0], 1u);
            if (b1 < HIST_MAX) atomicAdd(&h[b1], 1u);
            if (b2 < HIST_MAX) atomicAdd(&h[b2], 1u);
            if (b3 < HIST_MAX) atomicAdd(&h[b3], 1u);
        }
    }
    __syncthreads();
    if (t == 0) {
        unsigned int cum = 0; int cutbin = HIST_MAX - 1;
        for (int b = 0; b < HIST_MAX; ++b) {
            cum += h[b];
            if (cum >= KNEIGH) { cutbin = b; break; }
        }
        int tv = cutbin + MARGIN;
        thr_s = tv > 255 ? 255 : tv;
    }
    __syncthreads();
    const unsigned tv = (unsigned)thr_s;

    // pass 2: gather candidates into LDS
    for (int i = t; i < n16; i += 512) {
        uint4 v4 = qp[i];
#pragma unroll
        for (int dw = 0; dw < 4; ++dw) {
            uint32_t v = (&v4.x)[dw];
#pragma unroll
            for (int sub = 0; sub < 4; ++sub) {
                unsigned b = (v >> (8 * sub)) & 255u;
                if (b <= tv) {
                    int pos = atomicAdd(&nc_s, 1);
                    if (pos < CAND_CAP) candI[pos] = 16 * i + 4 * dw + sub;
                }
            }
        }
    }
    __syncthreads();
    const int nc = nc_s < CAND_CAP ? nc_s : CAND_CAP;

    // Phase A: fp32 distance, 16 lanes per candidate, coalesced 512B row reads
    {
        const int g = t >> 4;     // group 0..31
        const int gl = t & 15;    // lane within group
        float fr[8];
        const float* fpl = fsh + gl * 8;
#pragma unroll
        for (int j = 0; j < 8; ++j) fr[j] = fpl[j];
        for (int ci = g; ci < nc; ci += 32) {
            const float* cp = cent + (size_t)candI[ci] * DIM + gl * 8;
            float4 c0 = ((const float4*)cp)[0];
            float4 c1 = ((const float4*)cp)[1];
            float d0 = fr[0] - c0.x; float a = d0 * d0;
            float d1 = fr[1] - c0.y; a = fmaf(d1, d1, a);
            float d2 = fr[2] - c0.z; a = fmaf(d2, d2, a);
            float d3 = fr[3] - c0.w; a = fmaf(d3, d3, a);
            float d4 = fr[4] - c1.x; a = fmaf(d4, d4, a);
            float d5 = fr[5] - c1.y; a = fmaf(d5, d5, a);
            float d6 = fr[6] - c1.z; a = fmaf(d6, d6, a);
            float d7 = fr[7] - c1.w; a = fmaf(d7, d7, a);
            a += __shfl_xor(a, 8, 16);
            a += __shfl_xor(a, 4, 16);
            a += __shfl_xor(a, 2, 16);
            a += __shfl_xor(a, 1, 16);
            if (gl == 0) dist[ci] = a;
        }
    }
    __syncthreads();

    // Phase B: rank by (dist, idx); find 200th value
    for (int ci = t; ci < nc; ci += 512) {
        const float ki = dist[ci];
        const int ii = candI[ci];
        int rank = 0;
        for (int j = 0; j < nc; ++j) {
            float kj = dist[j];
            if (kj < ki || (kj == ki && candI[j] < ii)) rank++;
        }
        if (rank == KNEIGH - 1) cutVal_s = ki;
    }
    __syncthreads();
    const float cutVal = cutVal_s;

    // Phase C: classify def-in / band / def-out
    for (int ci = t; ci < nc; ci += 512) {
        const float d = dist[ci];
        if (d < cutVal - BAND_M) {
            atomicAdd(&nIn_s, 1);
            const int ii = candI[ci];
            float wv = expf(kw[ii] - d * GC);
            atomicAdd(&p[labels[ii]], wv);
        } else if (d <= cutVal + BAND_M) {
            int pos = atomicAdd(&nBand_s, 1);
            if (pos < BAND_CAP) bandCi[pos] = ci;
        }
    }
    __syncthreads();
    const int nIn = nIn_s;
    const int nBand = nBand_s < BAND_CAP ? nBand_s : BAND_CAP;
    const int needB = KNEIGH - nIn;
    const float fnr = fnrep[row];

    // Phase D: np-exact keys for band members only
    for (int i = t; i < nBand; i += 512) {
        const int idx = candI[bandCi[i]];
        const float* cp = cent + (size_t)idx * DIM;
        float acc = 0.f;
#pragma unroll
        for (int k = 0; k < DIM; ++k) acc = fmaf(2.0f * fsh[k], cp[k], acc);
        float cn = np_sum128_sq(cp);
        {
#pragma clang fp contract(off)
            bandKey[i] = (fnr - acc) + cn;
        }
    }
    __syncthreads();

    // Phase E: take needB smallest (npKey, idx) from band
    for (int i = t; i < nBand; i += 512) {
        const float ki = bandKey[i];
        const int ii = candI[bandCi[i]];
        int rank = 0;
        for (int j = 0; j < nBand; ++j) {
            float kj = bandKey[j];
            if (kj < ki || (kj == ki && candI[bandCi[j]] < ii)) rank++;
        }
        if (rank < needB) {
            float wv = expf(kw[ii] - dist[bandCi[i]] * GC);
            atomicAdd(&p[labels[ii]], wv);
        }
    }
    __syncthreads();

    // Phase F: normalize + log
    if (t == 0) {
        float s = 0.f;
        for (int c = 0; c < NCLASS; ++c) {
            float v = p[c];
            v = (v == 0.f) ? 1e-10f : v;
            p[c] = v;
            s += v;
        }
        ssum = s;
    }
    __syncthreads();
    for (int c = t; c < NCLASS; c += 512)
        out[(size_t)row * NCLASS + c] = logf(p[c] / ssum);
}

static inline size_t align256(size_t x) { return (x + 255) & ~(size_t)255; }

extern "C" void kernel_launch(void* const* d_in, const int* in_sizes, int n_in,
                              void* d_out, int out_size, void* d_ws, size_t ws_size,
                              hipStream_t stream) {
    const float* feat   = (const float*)d_in[0];  // [1024,128]
    const float* cent   = (const float*)d_in[1];  // [100000,128]
    const float* kw     = (const float*)d_in[2];  // [100000]
    const int*   labels = (const int*)d_in[3];    // [100000]
    float* out = (float*)d_out;                   // [1024,100]

    char* base = (char*)d_ws;
    size_t o = 0;
    unsigned short* centb  = (unsigned short*)(base + o); o += align256((size_t)NCENT * DIM * 2);
    unsigned short* featb  = (unsigned short*)(base + o); o += align256((size_t)BATCH * DIM * 2);
    float* cnorm           = (float*)(base + o);          o += align256((size_t)NCENT * 4);
    float* fnrep           = (float*)(base + o);          o += align256((size_t)BATCH * 4);
    unsigned char* qmat    = (unsigned char*)(base + o);  o += align256((size_t)BATCH * NCENT);
    (void)ws_size; (void)in_sizes; (void)n_in; (void)out_size;

    prep_cent_kernel<<<NCENT / 32, 256, 0, stream>>>(cent, centb, cnorm);
    prep_feat_kernel<<<(BATCH + 255) / 256, 256, 0, stream>>>(feat, featb, fnrep);

    dim3 gg((NCENT + 511) / 512, BATCH / 128);   // 196 x 8
    mfma_coarse_kernel<<<gg, 256, 0, stream>>>(featb, centb, cnorm, qmat);

    select_refine_kernel<<<BATCH, 512, 0, stream>>>(qmat, feat, cent, fnrep,
                                                    kw, labels, out);
}